// Round 5
// baseline (150.411 us; speedup 1.0000x reference)
//
#include <hip/hip_runtime.h>
#include <cstdint>
#include <cstddef>

#define CIN     16
#define CHID    16
#define T_DIM   31
#define HW_     16384            // 128*128
#define CH_STRIDE 507904         // 31*128*128
#define TILE_H  4
#define TILE_W  32
#define SH      6                // TILE_H + 2
#define SW      34               // TILE_W + 2
#define SPOS    (SH * SW)        // 204 positions
#define PSTR    24               // shorts per position (48B: bank-stride 12 -> 2-way, free)
#define SLICE_SH (SPOS * PSTR)   // 4896 shorts
#define SLICE_B  (SLICE_SH * 2)  // 9792 bytes
#define NSLOT   6                // 58,752 B LDS ring

typedef short bf16x8 __attribute__((ext_vector_type(8)));
typedef float f32x16 __attribute__((ext_vector_type(16)));

__device__ __forceinline__ unsigned bf16_bits(float x) {
  unsigned u = __builtin_bit_cast(unsigned, x);
  u += 0x7FFFu + ((u >> 16) & 1u);
  return u >> 16;
}
__device__ __forceinline__ unsigned cvt_pk_bf16(float lo, float hi) {
  unsigned r;
  asm("v_cvt_pk_bf16_f32 %0, %1, %2" : "=v"(r) : "v"(lo), "v"(hi));
  return r;
}

__global__ __launch_bounds__(256, 2)
void qrnn3d_v5(const float* __restrict__ in, const float* __restrict__ Wg,
               const float* __restrict__ bg, float* __restrict__ out) {
  __shared__ __align__(16) short xs[NSLOT][SLICE_SH];

  const int tid = threadIdx.x;
  const int bid = blockIdx.x;
  // XCD-chunked swizzle: XCD k owns 16 consecutive h-tiles x 4 w (h-halo L2 reuse)
  const int lin  = ((bid & 7) << 6) | (bid >> 3);
  const int b    = lin >> 7;
  const int tile = lin & 127;
  const int h0   = (tile >> 2) * TILE_H;
  const int w0   = (tile & 3) * TILE_W;

  const int lane = tid & 63;
  const int wid  = tid >> 6;
  const int col  = lane & 31;
  const int half = lane >> 5;

  // ---- weights -> 27 A-frags ----
  bf16x8 wfrag[27];
#pragma unroll
  for (int tau = 0; tau < 27; ++tau) {
    bf16x8 f;
#pragma unroll
    for (int j = 0; j < 8; ++j)
      f[j] = (short)bf16_bits(Wg[col * 432 + (half * 8 + j) * 27 + tau]);
    wfrag[tau] = f;
  }

  // ---- bias template + output byte offsets ----
  f32x16 accInit;
  unsigned voffB[8];
#pragma unroll
  for (int r = 0; r < 8; ++r) {
    int oc = (r & 3) + 8 * (r >> 2) + 4 * half;
    accInit[r]     = bg[oc];
    accInit[r + 8] = bg[oc + 16];
    voffB[r] = (unsigned)(((b * CHID + oc) * CH_STRIDE + (h0 + wid) * 128 + (w0 + col)) * 4);
  }

  // ---- staging geometry (t-invariant byte offsets) ----
  unsigned bo[16];   // global byte offsets from (in + tz*65536)
  unsigned lwb[4];   // LDS write byte offsets within slot
  unsigned msk[4];
  bool stv3 = false;
#pragma unroll
  for (int i = 0; i < 4; ++i) {
    int p   = tid + i * 256;
    int q   = p & 15, c4 = (p >> 4) & 3, j = p >> 6;
    int pos = j * 16 + q;
    bool stvi = (pos < SPOS);
    int hh = pos / SW, ww = pos - hh * SW;
    int gh = h0 + hh - 1, gw = w0 + ww - 1;
    bool ldvi = stvi && ((unsigned)gh < 128u) && ((unsigned)gw < 128u);
    int sp = ldvi ? (gh * 128 + gw) : 0;
#pragma unroll
    for (int k = 0; k < 4; ++k)
      bo[i * 4 + k] = (unsigned)(((b * CIN + c4 * 4 + k) * CH_STRIDE + sp) * 4);
    lwb[i] = (unsigned)(pos * (PSTR * 2) + c4 * 8);
    msk[i] = ldvi ? 0xFFFFFFFFu : 0u;
    if (i == 3) stv3 = stvi;
  }

#define LOADV(TZ, vv) do {                                                  \
    if ((TZ) <= 30) {                                                       \
      const char* bp_ = (const char*)in + (size_t)(TZ) * 65536;             \
      _Pragma("unroll") for (int i_ = 0; i_ < 4; ++i_) {                    \
        _Pragma("unroll") for (int k_ = 0; k_ < 4; ++k_)                    \
          vv[i_][k_] = *(const float*)(bp_ + bo[i_ * 4 + k_]);              \
      }                                                                     \
    } else {                                                                \
      _Pragma("unroll") for (int i_ = 0; i_ < 4; ++i_) {                    \
        _Pragma("unroll") for (int k_ = 0; k_ < 4; ++k_) vv[i_][k_] = 0.0f; \
      }                                                                     \
    }                                                                       \
  } while (0)

#define STOREV(vv, SLOTB) do {                                              \
    char* dp_ = (char*)&xs[0][0] + (SLOTB);                                 \
    _Pragma("unroll") for (int i_ = 0; i_ < 3; ++i_) {                      \
      uint2 u_;                                                             \
      u_.x = cvt_pk_bf16(vv[i_][0], vv[i_][1]) & msk[i_];                   \
      u_.y = cvt_pk_bf16(vv[i_][2], vv[i_][3]) & msk[i_];                   \
      *(uint2*)(dp_ + lwb[i_]) = u_;                                        \
    }                                                                       \
    if (stv3) {                                                             \
      uint2 u_;                                                             \
      u_.x = cvt_pk_bf16(vv[3][0], vv[3][1]) & msk[3];                      \
      u_.y = cvt_pk_bf16(vv[3][2], vv[3][3]) & msk[3];                      \
      *(uint2*)(dp_ + lwb[3]) = u_;                                         \
    }                                                                       \
  } while (0)

  const unsigned lbB = (unsigned)((wid * SW + col) * (PSTR * 2) + half * 16);

#define RD(SLOTB, U) (*(const bf16x8*)((const char*)&xs[0][0] + lbB + (SLOTB) + (((U) / 3) * SW + ((U) % 3)) * (PSTR * 2)))

  const float C_TANH = 2.8853900817779268f;   // 2*log2(e)
  const float C_SIG  = 1.4426950408889634f;   // log2(e)

  float hst[8];
#pragma unroll
  for (int r = 0; r < 8; ++r) hst[r] = 0.0f;

#define COMPUTE(T, AB, BB, CB) do {                                          \
    f32x16 acc1;                                                             \
    _Pragma("unroll") for (int q_ = 0; q_ < 16; ++q_) acc1[q_] = 0.0f;       \
    bf16x8 x0_ = RD(AB, 0);                                                  \
    f32x16 acc0 = __builtin_amdgcn_mfma_f32_32x32x16_bf16(wfrag[0], x0_, accInit, 0, 0, 0); \
    _Pragma("unroll") for (int u_ = 1; u_ < 9; ++u_) {                       \
      bf16x8 xx_ = RD(AB, u_);                                               \
      if (u_ & 1) acc1 = __builtin_amdgcn_mfma_f32_32x32x16_bf16(wfrag[u_], xx_, acc1, 0, 0, 0); \
      else        acc0 = __builtin_amdgcn_mfma_f32_32x32x16_bf16(wfrag[u_], xx_, acc0, 0, 0, 0); \
    }                                                                        \
    _Pragma("unroll") for (int u_ = 0; u_ < 9; ++u_) {                       \
      bf16x8 xx_ = RD(BB, u_);                                               \
      if ((9 + u_) & 1) acc1 = __builtin_amdgcn_mfma_f32_32x32x16_bf16(wfrag[9 + u_], xx_, acc1, 0, 0, 0); \
      else              acc0 = __builtin_amdgcn_mfma_f32_32x32x16_bf16(wfrag[9 + u_], xx_, acc0, 0, 0, 0); \
    }                                                                        \
    _Pragma("unroll") for (int u_ = 0; u_ < 9; ++u_) {                       \
      bf16x8 xx_ = RD(CB, u_);                                               \
      if ((18 + u_) & 1) acc1 = __builtin_amdgcn_mfma_f32_32x32x16_bf16(wfrag[18 + u_], xx_, acc1, 0, 0, 0); \
      else               acc0 = __builtin_amdgcn_mfma_f32_32x32x16_bf16(wfrag[18 + u_], xx_, acc0, 0, 0, 0); \
    }                                                                        \
    const char* outp_ = (const char*)out + (size_t)(T) * 65536;              \
    _Pragma("unroll") for (int r_ = 0; r_ < 8; ++r_) {                       \
      float zg_ = acc0[r_] + acc1[r_];                                       \
      float fg_ = acc0[r_ + 8] + acc1[r_ + 8];                               \
      float ez_ = exp2f(zg_ * C_TANH);                                       \
      float z_  = __builtin_fmaf(-2.0f, __builtin_amdgcn_rcpf(ez_ + 1.0f), 1.0f); \
      float ef_ = exp2f(-fg_ * C_SIG);                                       \
      float f_  = __builtin_amdgcn_rcpf(1.0f + ef_);                         \
      float h_  = __builtin_fmaf(f_, hst[r_] - z_, z_);                      \
      hst[r_]   = h_;                                                        \
      __builtin_nontemporal_store(h_, (float*)(outp_ + voffB[r_]));          \
    }                                                                        \
  } while (0)

#define BARRIER() do {                                                      \
    asm volatile("s_waitcnt lgkmcnt(0)" ::: "memory");                      \
    __builtin_amdgcn_s_barrier();                                           \
    __builtin_amdgcn_sched_barrier(0);                                      \
  } while (0)

  float vA[4][4], vB[4][4];
  // ---- prologue: slices 0,1,2 -> slots 0,1,2; slot5 = zeros (slice -1) ----
  LOADV(0, vA);
  LOADV(1, vB);
  STOREV(vA, 0 * SLICE_B);
  LOADV(2, vA);
  STOREV(vB, 1 * SLICE_B);
  STOREV(vA, 2 * SLICE_B);
  {
    unsigned* zp = (unsigned*)&xs[5][0];
    for (int i = tid; i < SLICE_SH / 2; i += 256) zp[i] = 0u;
  }
  BARRIER();
  LOADV(3, vA);

  // ---- main loop: 6-step unroll; raw barrier every 2 t-steps ----
#pragma unroll 1
  for (int tb = 0; tb < 30; tb += 6) {
    // j=0 (t even): write slot3, read 5/0/1
    LOADV(tb + 4, vB);
    STOREV(vA, 3 * SLICE_B);
    COMPUTE(tb + 0, 5 * SLICE_B, 0 * SLICE_B, 1 * SLICE_B);
    // j=1 (t odd): write slot4, read 0/1/2, barrier
    LOADV(tb + 5, vA);
    STOREV(vB, 4 * SLICE_B);
    COMPUTE(tb + 1, 0 * SLICE_B, 1 * SLICE_B, 2 * SLICE_B);
    BARRIER();
    // j=2: write slot5, read 1/2/3
    LOADV(tb + 6, vB);
    STOREV(vA, 5 * SLICE_B);
    COMPUTE(tb + 2, 1 * SLICE_B, 2 * SLICE_B, 3 * SLICE_B);
    // j=3: write slot0, read 2/3/4, barrier
    LOADV(tb + 7, vA);
    STOREV(vB, 0 * SLICE_B);
    COMPUTE(tb + 3, 2 * SLICE_B, 3 * SLICE_B, 4 * SLICE_B);
    BARRIER();
    // j=4: write slot1, read 3/4/5
    LOADV(tb + 8, vB);
    STOREV(vA, 1 * SLICE_B);
    COMPUTE(tb + 4, 3 * SLICE_B, 4 * SLICE_B, 5 * SLICE_B);
    // j=5: write slot2 (slice tb+8; skip when > 31), read 4/5/0, barrier
    LOADV(tb + 9, vA);
    if (tb + 5 <= 28) STOREV(vB, 2 * SLICE_B);
    COMPUTE(tb + 5, 4 * SLICE_B, 5 * SLICE_B, 0 * SLICE_B);
    BARRIER();
  }
  // tail t=30: read 5/0/1
  COMPUTE(30, 5 * SLICE_B, 0 * SLICE_B, 1 * SLICE_B);

#undef LOADV
#undef STOREV
#undef RD
#undef COMPUTE
#undef BARRIER
}

extern "C" void kernel_launch(void* const* d_in, const int* in_sizes, int n_in,
                              void* d_out, int out_size, void* d_ws, size_t ws_size,
                              hipStream_t stream) {
  const float* in = (const float*)d_in[0];
  const float* Wg = (const float*)d_in[1];
  const float* bg = (const float*)d_in[2];
  float* out      = (float*)d_out;
  (void)in_sizes; (void)n_in; (void)out_size; (void)d_ws; (void)ws_size;
  qrnn3d_v5<<<dim3(512), dim3(256), 0, stream>>>(in, Wg, bg, out);
}